// Round 20
// baseline (2365.355 us; speedup 1.0000x reference)
//
#include <hip/hip_runtime.h>
#include <hip/hip_bf16.h>

#define H1 1024
#define FOURH 4096
#define BATCH 512
#define SEQ 64
#define DIN 128
#define TDEC 8
#define SCR 68

typedef float f32x4 __attribute__((ext_vector_type(4)));
typedef _Float16 f16x8 __attribute__((ext_vector_type(8)));
typedef __bf16 bf16x8 __attribute__((ext_vector_type(8)));

// global->LDS direct, 16B per lane. LDS dest is wave-uniform base + lane*16.
__device__ __forceinline__ void gl_lds16(const void* g, void* l) {
    __builtin_amdgcn_global_load_lds(
        (const __attribute__((address_space(1))) unsigned int*)g,
        (__attribute__((address_space(3))) unsigned int*)l, 16, 0, 0);
}

// ---------------------------------------------------------------------------
// Weights [4096][K] f32 -> permuted SINGLE fp16 [dr][K].
// dr = uc*64 + c (unit uc*16+(c>>2), gate c&3; src row (c&3)*1024+uc*16+(c>>2)).
// ---------------------------------------------------------------------------
__global__ __launch_bounds__(256) void conv_wf16_k(
    const float* __restrict__ src, _Float16* __restrict__ dst, int K, int ks3)
{
    int i  = blockIdx.x * 256 + threadIdx.x;         // piece = 8 elems
    int c  = i & 63;
    int kk = (i >> 6) & ((K >> 3) - 1);
    int uc = i >> (6 + ks3);
    int r  = (c & 3) * 1024 + uc * 16 + (c >> 2);
    const float* s = src + (size_t)r * K + kk * 8;
    f16x8 p;
#pragma unroll
    for (int e = 0; e < 8; ++e) p[e] = (_Float16)s[e];
    *(f16x8*)(dst + (size_t)(uc * 64 + c) * K + kk * 8) = p;
}

// x [R][K] f32 -> single fp16, plain row layout.
__global__ __launch_bounds__(256) void conv_xf16_k(
    const float* __restrict__ src, _Float16* __restrict__ dst, int total8)
{
    int i = blockIdx.x * 256 + threadIdx.x;
    if (i >= total8) return;
    const float* s = src + (size_t)i * 8;
    f16x8 p;
#pragma unroll
    for (int e = 0; e < 8; ++e) p[e] = (_Float16)s[e];
    *(f16x8*)(dst + (size_t)i * 8) = p;
}

// ---------------------------------------------------------------------------
// Fused GEMM + LSTM cell, fp16 operands, 8-WAVE variant (512 threads).
// Identical tile/grid/schedule/bytes to the 2336us 4-wave kernel; the only
// change: each 16KB stage is issued by 8 waves x 2 loads instead of
// 4 x 4 (tests the per-wave issue-pacing hypothesis for the ~10.5 B/cyc/
// block staging-fill wall; r8/r13 evidence: rate ∝ resident blocks).
// Block = 64 batch x 64 gate-cols (16 units). grid 512 = 8 bm x 64 uc.
// 8 waves = 4m x 2n, wave tile 16x32 (1x2 frags 16x16x32 f16). LDS ring
// 3 x 16KB = 48KB static -> 2 blocks/CU (1024 thr, 96KB). Depth-2 prefetch,
// vmcnt(2)/(0). c state f32; h out single fp16 [row][1024].
// ---------------------------------------------------------------------------
__global__ __launch_bounds__(512, 2) void lstm_fs8(
    const char* __restrict__ a0, long long a0row_b, int k0,
    const char* __restrict__ a1,                     // h fp16, row 2048 B
    const _Float16* __restrict__ w0f,                // permuted fp16, row 2*k0 B
    const _Float16* __restrict__ w1f,                // permuted fp16, row 2048 B
    const float* __restrict__ bias,
    float* __restrict__ cst, _Float16* __restrict__ hout)
{
    __shared__ char smem[49152];                     // 3 bufs x (A 8KB + B 8KB)
    const int tid  = threadIdx.x;
    const int lane = tid & 63;
    const int w    = tid >> 6;                       // wave 0..7
    const int wm   = w >> 1;                         // 0..3 (16-row group)
    const int wn   = w & 1;                          // 0..1 (32-col group)
    const int wg   = blockIdx.x;
    const int bm   = wg >> 6;                        // 0..7
    const int uc   = wg & 63;                        // 0..63

    const int nA = k0 >> 6;                          // super-chunks in seg 0
    const int n  = nA + 16;                          // + recurrent (1024/64)

    // ---- staging geometry: 2 gl_lds16 per wave per chunk (A 1 + B 1) ----
    const int rsub = lane >> 3;
    const int slot = lane & 7;
    const int gsw  = slot ^ rsub;                    // XOR-swizzled src granule

    const char* pa0; const char* pa1v;
    const char* pb0; const char* pb1v;
    {
        int ar = bm * 64 + w * 8 + rsub;             // A row (8 rows per wave)
        pa0  = a0 + (size_t)ar * a0row_b + gsw * 16;
        pa1v = a1 + (size_t)ar * 2048 + gsw * 16;
        int c  = w * 8 + rsub;                       // B row (gate-col)
        int dr = uc * 64 + c;
        pb0  = (const char*)w0f + (size_t)dr * (2 * (size_t)k0) + gsw * 16;
        pb1v = (const char*)w1f + (size_t)dr * 2048 + gsw * 16;
    }

    // LDS dests wave-uniform (HW adds lane*16); wave w covers rows w*8..+8
    // (1024B per gl_lds16) in each 8KB plane.
    auto stage = [&](int c, int buf) {
        char* bufA = smem + buf * 16384;
        char* bufB = bufA + 8192;
        const char* pa = (c < nA) ? pa0 : pa1v;
        const char* pb = (c < nA) ? pb0 : pb1v;
        size_t kb = (size_t)((c < nA) ? c : c - nA) * 128;
        gl_lds16(pa + kb, bufA + w * 1024);
        gl_lds16(pb + kb, bufB + w * 1024);
    };

    // ---- fragment geometry (wave tile 16x32) ----
    const int rA = wm * 16 + (lane & 15);            // batch row in 64-tile
    int rB[2];
#pragma unroll
    for (int f = 0; f < 2; ++f) rB[f] = wn * 32 + f * 16 + (lane & 15);
    const int s7 = lane & 7;
    const int g0 = lane >> 4;                        // k-granule group 0..3

    f32x4 acc[2];
    acc[0] = (f32x4){0.f, 0.f, 0.f, 0.f};
    acc[1] = (f32x4){0.f, 0.f, 0.f, 0.f};

    auto chunk = [&](int buf) {
        char* bufA = smem + buf * 16384;
        char* bufB = bufA + 8192;
        f16x8 aa[2], bb[2][2];
#pragma unroll
        for (int s = 0; s < 2; ++s) {
            int gx = ((g0 + s * 4) ^ s7) * 16;
            aa[s] = *(const f16x8*)(bufA + rA * 128 + gx);
#pragma unroll
            for (int f = 0; f < 2; ++f)
                bb[f][s] = *(const f16x8*)(bufB + rB[f] * 128 + gx);
        }
#pragma unroll
        for (int nf = 0; nf < 2; ++nf)
#pragma unroll
            for (int s = 0; s < 2; ++s)
                acc[nf] = __builtin_amdgcn_mfma_f32_16x16x32_f16(
                    aa[s], bb[nf][s], acc[nf], 0, 0, 0);
    };

    stage(0, 0);
    stage(1, 1);

    for (int i = 0; i < n; ++i) {
        if (i + 1 < n) asm volatile("s_waitcnt vmcnt(2)" ::: "memory");
        else           asm volatile("s_waitcnt vmcnt(0)" ::: "memory");
        __builtin_amdgcn_sched_barrier(0);
        __builtin_amdgcn_s_barrier();
        __builtin_amdgcn_sched_barrier(0);

        if (i + 2 < n) {
            int b2 = i + 2; while (b2 >= 3) b2 -= 3;
            stage(i + 2, b2);
        }

        int bi = i; while (bi >= 3) bi -= 3;
        chunk(bi);
        __builtin_amdgcn_sched_barrier(0);
    }

    // ---- epilogue: acc -> LDS scratch [64][SCR] f32 ----
    __syncthreads();
    float* scr = (float*)smem;
#pragma unroll
    for (int nf = 0; nf < 2; ++nf) {
        int row0 = wm * 16 + (lane >> 4) * 4;        // m89 C layout
        int col  = wn * 32 + nf * 16 + (lane & 15);
#pragma unroll
        for (int j = 0; j < 4; ++j)
            scr[(row0 + j) * SCR + col] = acc[nf][j];
    }
    __syncthreads();

    // ---- in-block cell: 64 rows x 16 units = 1024 items / 512 thr ----
#pragma unroll
    for (int p = 0; p < 2; ++p) {
        int item = p * 512 + tid;
        int u = item & 15;
        int r = item >> 4;                           // 0..63
        f32x4 g4 = *(const f32x4*)(scr + r * SCR + u * 4);
        int gu = uc * 16 + u;
        float gi = g4[0] + bias[gu];
        float gf = g4[1] + bias[H1 + gu];
        float gg = g4[2] + bias[2 * H1 + gu];
        float go = g4[3] + bias[3 * H1 + gu];
        float si = 1.f / (1.f + expf(-gi));
        float sf = 1.f / (1.f + expf(-gf));
        float so = 1.f / (1.f + expf(-go));
        int row_g = bm * 64 + r;
        size_t ci = (size_t)row_g * H1 + gu;
        float cc = sf * cst[ci] + si * tanhf(gg);
        cst[ci] = cc;
        hout[(size_t)row_g * H1 + gu] = (_Float16)(so * tanhf(cc));
    }
}

// ---------------------------------------------------------------------------
// head on fp16 h: 16 lanes per output (64 elems each), shfl_xor reduce.
// ---------------------------------------------------------------------------
__global__ __launch_bounds__(256) void head_fs_k(
    const _Float16* __restrict__ hp, const float* __restrict__ W,
    const float* __restrict__ bo, float* __restrict__ out)
{
    int gid = blockIdx.x * 16 + (threadIdx.x >> 4);  // output 0..8191
    int l16 = threadIdx.x & 15;
    int b = gid >> 4, o = gid & 15;
    const _Float16* hr = hp + (size_t)b * H1 + l16 * 64;
    const float*    wr = W + (size_t)o * H1 + l16 * 64;
    float s = 0.f;
#pragma unroll
    for (int j8 = 0; j8 < 8; ++j8) {
        f16x8 v = *(const f16x8*)(hr + j8 * 8);
        const f32x4* wv = (const f32x4*)(wr + j8 * 8);
        f32x4 w0 = wv[0], w1 = wv[1];
#pragma unroll
        for (int e = 0; e < 4; ++e)
            s += (float)v[e] * w0[e];
#pragma unroll
        for (int e = 4; e < 8; ++e)
            s += (float)v[e] * w1[e - 4];
    }
#pragma unroll
    for (int m = 8; m >= 1; m >>= 1)
        s += __shfl_xor(s, m, 16);
    if (l16 == 0) {
        float v = s + bo[o];
        out[(size_t)b * 32 + o]      = v;
        out[(size_t)b * 32 + 16 + o] = v;
    }
}

// ---------------------------------------------------------------------------
// FALLBACK (r9/r10-proven f32 all-LDS path) — runs only if ws too small.
// ---------------------------------------------------------------------------
__global__ __launch_bounds__(256, 1) void lstm_fused_f32(
    const float* __restrict__ a0v, long long arow_b, int k0,
    const float* __restrict__ w0v,
    const float* __restrict__ a1v,
    const float* __restrict__ w1v,
    const float* __restrict__ bias,
    float* __restrict__ cst, float* __restrict__ houtv)
{
    extern __shared__ char smem[];
    const int tid  = threadIdx.x;
    const int lane = tid & 63;
    const int w    = tid >> 6;
    const int wm   = w >> 1, wn = w & 1;
    const int wg   = blockIdx.x;
    const int bm   = wg >> 5;
    const int uc   = wg & 31;

    const int nA = k0 >> 5;
    const int n  = nA + 32;

    const int rsub = lane >> 3;
    const int slot = lane & 7;
    const int gsw  = slot ^ rsub;

    const char* paj0[2]; const char* paj1[2];
    const char* pbj0[4]; const char* pbj1[4];
#pragma unroll
    for (int j = 0; j < 2; ++j) {
        int ar = bm * 64 + w * 16 + j * 8 + rsub;
        paj0[j] = (const char*)a0v + (size_t)ar * arow_b + gsw * 16;
        paj1[j] = (const char*)a1v + (size_t)ar * 4096 + gsw * 16;
    }
#pragma unroll
    for (int j = 0; j < 4; ++j) {
        int c = w * 32 + j * 8 + rsub;
        int br0 = (c & 3) * H1 + uc * 32 + (c >> 2);
        pbj0[j] = (const char*)w0v + (size_t)br0 * (4 * (size_t)k0) + gsw * 16;
        pbj1[j] = (const char*)w1v + (size_t)br0 * 4096 + gsw * 16;
    }

    auto stage = [&](int ii, int buf) {
        char* bufA = smem + buf * 24576;
        char* bufB = bufA + 8192;
        size_t kb = (ii < nA) ? (size_t)ii * 128 : (size_t)(ii - nA) * 128;
        const char* const* pa = (ii < nA) ? paj0 : paj1;
        const char* const* pb = (ii < nA) ? pbj0 : pbj1;
#pragma unroll
        for (int j = 0; j < 2; ++j)
            gl_lds16(pa[j] + kb, bufA + (w * 2 + j) * 1024);
#pragma unroll
        for (int j = 0; j < 4; ++j)
            gl_lds16(pb[j] + kb, bufB + (w * 4 + j) * 1024);
    };

    int rAv[2], rBv[4];
#pragma unroll
    for (int f = 0; f < 2; ++f) rAv[f] = wm * 32 + f * 16 + (lane & 15);
#pragma unroll
    for (int f = 0; f < 4; ++f) rBv[f] = wn * 64 + f * 16 + (lane & 15);
    const int s7 = lane & 7;
    const int g0 = lane >> 4;

    f32x4 acc[2][4];
#pragma unroll
    for (int mf = 0; mf < 2; ++mf)
#pragma unroll
        for (int nf = 0; nf < 4; ++nf)
            acc[mf][nf] = (f32x4){0.f, 0.f, 0.f, 0.f};

    stage(0, 0); stage(1, 1); stage(2, 2); stage(3, 3); stage(4, 4);

    int buf = 0;
    for (int i = 0; i < n; ++i) {
        const int rem = n - i;
        if (rem >= 5)      asm volatile("s_waitcnt vmcnt(24)" ::: "memory");
        else if (rem == 4) asm volatile("s_waitcnt vmcnt(18)" ::: "memory");
        else if (rem == 3) asm volatile("s_waitcnt vmcnt(12)" ::: "memory");
        else if (rem == 2) asm volatile("s_waitcnt vmcnt(6)"  ::: "memory");
        else               asm volatile("s_waitcnt vmcnt(0)"  ::: "memory");
        __builtin_amdgcn_sched_barrier(0);
        __builtin_amdgcn_s_barrier();
        __builtin_amdgcn_sched_barrier(0);

        if (i + 5 < n) {
            int b5 = buf + 5; if (b5 >= 6) b5 -= 6;
            stage(i + 5, b5);
        }

        char* bufA = smem + buf * 24576;
        char* bufB = bufA + 8192;

        bf16x8 ah[2], al[2], bh[4], bl[4];
#pragma unroll
        for (int f = 0; f < 2; ++f) {
            f32x4 v0 = *(const f32x4*)(bufA + rAv[f] * 128 + ((2 * g0    ) ^ s7) * 16);
            f32x4 v1 = *(const f32x4*)(bufA + rAv[f] * 128 + ((2 * g0 + 1) ^ s7) * 16);
#pragma unroll
            for (int e = 0; e < 4; ++e) {
                __bf16 h0 = (__bf16)v0[e];
                ah[f][e] = h0; al[f][e] = (__bf16)(v0[e] - (float)h0);
                __bf16 h1 = (__bf16)v1[e];
                ah[f][e + 4] = h1; al[f][e + 4] = (__bf16)(v1[e] - (float)h1);
            }
        }
#pragma unroll
        for (int f = 0; f < 4; ++f) {
            f32x4 u0 = *(const f32x4*)(bufB + rBv[f] * 128 + ((2 * g0    ) ^ s7) * 16);
            f32x4 u1 = *(const f32x4*)(bufB + rBv[f] * 128 + ((2 * g0 + 1) ^ s7) * 16);
#pragma unroll
            for (int e = 0; e < 4; ++e) {
                __bf16 h0 = (__bf16)u0[e];
                bh[f][e] = h0; bl[f][e] = (__bf16)(u0[e] - (float)h0);
                __bf16 h1 = (__bf16)u1[e];
                bh[f][e + 4] = h1; bl[f][e + 4] = (__bf16)(u1[e] - (float)h1);
            }
        }
#pragma unroll
        for (int mf = 0; mf < 2; ++mf)
#pragma unroll
            for (int nf = 0; nf < 4; ++nf) {
                acc[mf][nf] = __builtin_amdgcn_mfma_f32_16x16x32_bf16(
                    ah[mf], bh[nf], acc[mf][nf], 0, 0, 0);
                acc[mf][nf] = __builtin_amdgcn_mfma_f32_16x16x32_bf16(
                    ah[mf], bl[nf], acc[mf][nf], 0, 0, 0);
                acc[mf][nf] = __builtin_amdgcn_mfma_f32_16x16x32_bf16(
                    al[mf], bh[nf], acc[mf][nf], 0, 0, 0);
            }
        __builtin_amdgcn_sched_barrier(0);
        buf = buf + 1; if (buf >= 6) buf -= 6;
    }

    __syncthreads();
    float* scr = (float*)smem;
#pragma unroll
    for (int mf = 0; mf < 2; ++mf)
#pragma unroll
        for (int nf = 0; nf < 4; ++nf) {
            int row0 = wm * 32 + mf * 16 + (lane >> 4) * 4;
            int col  = wn * 64 + nf * 16 + (lane & 15);
#pragma unroll
            for (int j = 0; j < 4; ++j)
                scr[(row0 + j) * 128 + col] = acc[mf][nf][j];
        }
    __syncthreads();

#pragma unroll
    for (int p = 0; p < 8; ++p) {
        int item = p * 256 + tid;
        int u = item & 31;
        int r = item >> 5;
        f32x4 g4 = *(const f32x4*)(scr + r * 128 + u * 4);
        int gu = uc * 32 + u;
        float gi = g4[0] + bias[gu];
        float gf = g4[1] + bias[H1 + gu];
        float gg = g4[2] + bias[2 * H1 + gu];
        float go = g4[3] + bias[3 * H1 + gu];
        float si = 1.f / (1.f + expf(-gi));
        float sf = 1.f / (1.f + expf(-gf));
        float so = 1.f / (1.f + expf(-go));
        size_t ci = (size_t)(bm * 64 + r) * H1 + gu;
        float cc = sf * cst[ci] + si * tanhf(gg);
        cst[ci] = cc;
        houtv[ci] = so * tanhf(cc);
    }
}

__global__ __launch_bounds__(256) void head_k(
    const float* __restrict__ h, const float* __restrict__ W,
    const float* __restrict__ bo, float* __restrict__ out)
{
    int idx = blockIdx.x * 256 + threadIdx.x;
    int b = idx >> 4, o = idx & 15;
    const f32x4* hv = (const f32x4*)(h + (size_t)b * H1);
    const f32x4* wv = (const f32x4*)(W + (size_t)o * H1);
    float s = bo[o];
#pragma unroll 4
    for (int k = 0; k < H1 / 4; ++k) {
        f32x4 a = hv[k];
        f32x4 wq = wv[k];
        s += a[0] * wq[0] + a[1] * wq[1] + a[2] * wq[2] + a[3] * wq[3];
    }
    out[(size_t)b * 32 + o]      = s;
    out[(size_t)b * 32 + 16 + o] = s;
}

// ===========================================================================
extern "C" void kernel_launch(void* const* d_in, const int* in_sizes, int n_in,
                              void* d_out, int out_size, void* d_ws, size_t ws_size,
                              hipStream_t stream)
{
    const float* x    = (const float*)d_in[0];
    const float* Wih0 = (const float*)d_in[1];
    const float* Whh0 = (const float*)d_in[2];
    const float* b0   = (const float*)d_in[3];
    const float* Wih1 = (const float*)d_in[4];
    const float* Whh1 = (const float*)d_in[5];
    const float* b1   = (const float*)d_in[6];
    const float* dWih = (const float*)d_in[7];
    const float* dWhh = (const float*)d_in[8];
    const float* db   = (const float*)d_in[9];
    const float* Wout = (const float*)d_in[10];
    const float* bout = (const float*)d_in[11];

    dim3 blk(256);
    const size_t WF_SMALL = (size_t)4096 * 128 * 2;    // 1MB  fp16 K=128
    const size_t WF_BIG   = (size_t)4096 * 1024 * 2;   // 8MB  fp16 K=1024
    const size_t XSB      = (size_t)BATCH * SEQ * 128 * 2; // 8MB x fp16
    const size_t HSB      = (size_t)BATCH * H1 * 2;    // 1MB  h fp16
    const size_t CSZ      = (size_t)BATCH * H1;        // elems
    const size_t NEED1    = WF_SMALL + 7 * WF_BIG + XSB + 4 * HSB + 2 * CSZ * 4;

    const float* dWih1 = dWih + (size_t)FOURH * H1;
    const float* dWhh1 = dWhh + (size_t)FOURH * H1;

    if (ws_size >= NEED1) {
        // ---------------- fp16 single path (8-wave) ----------------
        char* wsb = (char*)d_ws;
        _Float16* Wih0f  = (_Float16*)wsb;
        _Float16* Whh0f  = (_Float16*)(wsb + WF_SMALL);
        _Float16* Wih1f  = (_Float16*)(wsb + WF_SMALL + WF_BIG);
        _Float16* Whh1f  = (_Float16*)(wsb + WF_SMALL + 2 * WF_BIG);
        _Float16* dWih0f = (_Float16*)(wsb + WF_SMALL + 3 * WF_BIG);
        _Float16* dWhh0f = (_Float16*)(wsb + WF_SMALL + 4 * WF_BIG);
        _Float16* dWih1f = (_Float16*)(wsb + WF_SMALL + 5 * WF_BIG);
        _Float16* dWhh1f = (_Float16*)(wsb + WF_SMALL + 6 * WF_BIG);
        char* sb = wsb + WF_SMALL + 7 * WF_BIG;
        _Float16* xp   = (_Float16*)sb;
        _Float16* hp0a = (_Float16*)(sb + XSB);
        _Float16* hp0b = (_Float16*)(sb + XSB + HSB);
        _Float16* hp1a = (_Float16*)(sb + XSB + 2 * HSB);
        _Float16* hp1b = (_Float16*)(sb + XSB + 3 * HSB);
        float*    c0   = (float*)(sb + XSB + 4 * HSB);
        float*    c1   = c0 + CSZ;

        auto convw = [&](const float* s, _Float16* d, int K, int ks3) {
            int total = 4096 * (K >> 3);
            conv_wf16_k<<<dim3(total / 256), blk, 0, stream>>>(s, d, K, ks3);
        };
        convw(Wih0, Wih0f, 128, 4);
        convw(Whh0, Whh0f, 1024, 7);
        convw(Wih1, Wih1f, 1024, 7);
        convw(Whh1, Whh1f, 1024, 7);
        convw(dWih,  dWih0f, 1024, 7);
        convw(dWih1, dWih1f, 1024, 7);
        convw(dWhh,  dWhh0f, 1024, 7);
        convw(dWhh1, dWhh1f, 1024, 7);
        {
            int total8 = BATCH * SEQ * 16;           // x: rows 32768, K=128
            conv_xf16_k<<<dim3((total8 + 255) / 256), blk, 0, stream>>>(x, xp, total8);
        }

        hipMemsetAsync(hp0a, 0, 4 * HSB + 2 * CSZ * 4, stream);

        dim3 fgrid(512);
        dim3 fblk(512);
        _Float16 *hc = hp0a, *hn = hp0b, *h1c = hp1a, *h1n = hp1b;
        const long long XROW = (long long)(SEQ * 128 * 2);  // x row bytes
        for (int t = 0; t < SEQ; ++t) {
            lstm_fs8<<<fgrid, fblk, 0, stream>>>(
                (const char*)xp + (size_t)t * 256, XROW, DIN,
                (const char*)hc, Wih0f, Whh0f, b0, c0, hn);
            lstm_fs8<<<fgrid, fblk, 0, stream>>>(
                (const char*)hn, 2048LL, H1,
                (const char*)h1c, Wih1f, Whh1f, b1, c1, h1n);
            _Float16* t0 = hc; hc = hn; hn = t0;
            _Float16* t1 = h1c; h1c = h1n; h1n = t1;
        }
        for (int s = 0; s < TDEC; ++s) {
            lstm_fs8<<<fgrid, fblk, 0, stream>>>(
                (const char*)h1c, 2048LL, H1,
                (const char*)hc, dWih0f, dWhh0f, db, c0, hn);
            lstm_fs8<<<fgrid, fblk, 0, stream>>>(
                (const char*)hn, 2048LL, H1,
                (const char*)h1c, dWih1f, dWhh1f, db + FOURH, c1, h1n);
            _Float16* t0 = hc; hc = hn; hn = t0;
            _Float16* t1 = h1c; h1c = h1n; h1n = t1;
        }
        head_fs_k<<<dim3(512), blk, 0, stream>>>(h1c, Wout, bout, (float*)d_out);
    } else {
        // ---------------- f32 fallback (proven) ----------------
        float* h0a = (float*)d_ws;
        float* h0b = h0a + CSZ;
        float* h1a = h0b + CSZ;
        float* h1b = h1a + CSZ;
        float* c0  = h1b + CSZ;
        float* c1  = c0 + CSZ;
        hipMemsetAsync(h0a, 0, 6 * CSZ * 4, stream);

        (void)hipFuncSetAttribute(reinterpret_cast<const void*>(&lstm_fused_f32),
                                  hipFuncAttributeMaxDynamicSharedMemorySize, 147456);

        dim3 oldgrid(256);
        float *hc = h0a, *hn = h0b, *h1c = h1a, *h1n = h1b;
        for (int t = 0; t < SEQ; ++t) {
            lstm_fused_f32<<<oldgrid, blk, 147456, stream>>>(
                x + (size_t)t * DIN, (long long)(SEQ * DIN * 4), DIN, Wih0,
                hc, Whh0, b0, c0, hn);
            lstm_fused_f32<<<oldgrid, blk, 147456, stream>>>(
                hn, 4096LL, H1, Wih1, h1c, Whh1, b1, c1, h1n);
            float* t0 = hc; hc = hn; hn = t0;
            float* t1 = h1c; h1c = h1n; h1n = t1;
        }
        for (int s = 0; s < TDEC; ++s) {
            lstm_fused_f32<<<oldgrid, blk, 147456, stream>>>(
                h1c, 4096LL, H1, dWih, hc, dWhh, db, c0, hn);
            lstm_fused_f32<<<oldgrid, blk, 147456, stream>>>(
                hn, 4096LL, H1, dWih1, h1c, dWhh1, db + FOURH, c1, h1n);
            float* t0 = hc; hc = hn; hn = t0;
            float* t1 = h1c; h1c = h1n; h1n = t1;
        }
        head_k<<<dim3(32), blk, 0, stream>>>(h1c, Wout, bout, (float*)d_out);
    }
}